// Round 9
// baseline (475.544 us; speedup 1.0000x reference)
//
#include <hip/hip_runtime.h>
#include <hip/hip_bf16.h>

// GGNN fused scan v12. B=128, N=128, E=64, T=32, R=32.
// ggnn_pre: v2 (unchanged).
// ggnn_main v12 (from v11): ALL FOUR w3 weight tables in LDS.
//   v11 kept wcr/wcz[128] as "register" arrays but VGPR_Count=132 proved the
//   allocator spilled them -> per-step scratch reloads inside the r/z matvec.
//   Now Wr_bot/Wz_bot/Wt_bot/W_in_top all live in LDS [tbl][kc][e] float4
//   (64 KB); matvec loops read loop-invariant ds_read_b128 -> no scratch, and
//   the LDS pipe time overlaps the VALU chain. w3 is nearly register-free.
//   Everything else identical to v11 (1 barrier/step, pre-zeroed subdiag,
//   +INF sentinel, patch-input prefetch).

#define B_ 128
#define N_ 128

typedef unsigned short u16;
typedef unsigned int u32;

__device__ __forceinline__ float b2f(u16 u) {
    union { u32 i; float f; } c; c.i = ((u32)u) << 16; return c.f;
}
__device__ __forceinline__ u16 f2b(float f) {
    union { float f; u32 i; } c; c.f = f;
    u32 u = c.i;
    return (u16)((u + 0x7fffu + ((u >> 16) & 1u)) >> 16);
}
__device__ __forceinline__ float sigmoidf_(float x) { return 1.0f / (1.0f + __expf(-x)); }
__device__ __forceinline__ float tanhf_(float x) { return 1.0f - 2.0f / (__expf(2.0f * x) + 1.0f); }
__device__ __forceinline__ float rlane(float v, int k) {
    return __int_as_float(__builtin_amdgcn_readlane(__float_as_int(v), k));
}
#define BARRIER() asm volatile("s_waitcnt lgkmcnt(0)\n\ts_barrier" ::: "memory")

// pair-layout partial -> lane-e max, written to pmax slot
__device__ __forceinline__ void combine_write(float mA, float mB, int e,
                                              float* __restrict__ slotbase)
{
    int s0 = (e >> 1) << 2, s1 = ((e >> 1) + 32) << 2;
    float v0a = __int_as_float(__builtin_amdgcn_ds_bpermute(s0, __float_as_int(mA)));
    float v0b = __int_as_float(__builtin_amdgcn_ds_bpermute(s0, __float_as_int(mB)));
    float v1a = __int_as_float(__builtin_amdgcn_ds_bpermute(s1, __float_as_int(mA)));
    float v1b = __int_as_float(__builtin_amdgcn_ds_bpermute(s1, __float_as_int(mB)));
    float c0 = (e & 1) ? v0b : v0a;
    float c1 = (e & 1) ? v1b : v1a;
    slotbase[e] = fmaxf(c0, c1);
}

// B-wave scan loop: NJ = per-half j count (24 for w0/w1, 16 for w2).
// No masking: subdiagonal bytes are pre-zeroed; relW32[0] = +INF sentinel.
template<int NJ>
__device__ __forceinline__ void bloop(
    int b, int w, int e, int p, int half, int len,
    const float* __restrict__ Hws,
    const unsigned char* __restrict__ relL,
    const u32* __restrict__ relW32,
    const float* __restrict__ disc,
    float* __restrict__ pmaxF,            // [2*192]
    const float* __restrict__ updH)
{
    const float NEGINF = -__builtin_inff();
    const int base = w * 48 + half * NJ;

    float hA[NJ], hB[NJ], dreg[NJ];
    {
        const float2* H2 = (const float2*)(Hws + (size_t)b * N_ * 64);
        #pragma unroll
        for (int jj = 0; jj < NJ; ++jj) {
            float2 v = H2[(base + jj) * 32 + p];
            hA[jj] = v.x; hB[jj] = v.y;
            dreg[jj] = disc[base + jj];
        }
    }

    // prologue: pmax[0] over all j (row 0 has no zeroed bytes)
    {
        float mA = NEGINF, mB = NEGINF;
        const u32* rw = (const u32*)(relL + base);
        #pragma unroll
        for (int g = 0; g < NJ / 4; ++g) {
            u32 d = rw[g];
            #pragma unroll
            for (int bb = 0; bb < 4; ++bb) {
                const int jj = 4 * g + bb;
                u32 rr = (d >> (bb * 8)) & 255u;
                u32 pr = relW32[(rr << 5) + p];
                float rwbA = __uint_as_float(pr << 16);
                float rwbB = __uint_as_float(pr & 0xffff0000u);
                float dd = dreg[jj];
                mA = fmaxf(mA, fmaxf(hA[jj] + rwbA, 0.f) * dd);
                mB = fmaxf(mB, fmaxf(hB[jj] + rwbB, 0.f) * dd);
            }
        }
        combine_write(mA, mB, e, pmaxF + (w << 6));
    }
    BARRIER();                                            // prologue barrier

    for (int i = 0; i < len; ++i) {
        if (i > 0) {                                      // merge row i-1
            const int prev = i - 1;
            const int ow = (prev < 48) ? 0 : (prev < 96) ? 1 : 2;
            if (w == ow) {
                float2 u = ((const float2*)updH)[p];
                const int off = prev - ow * 48;
                const int hs = (off >= NJ) ? 1 : 0;
                const int oj = off - hs * NJ;
                if (half == hs) {
                    #pragma unroll
                    for (int jj = 0; jj < NJ; ++jj) if (jj == oj) {
                        hA[jj] = u.x; hB[jj] = u.y;
                    }
                }
            }
        }
        if (i + 1 < len) {                                // pmax for step i+1
            float mA = NEGINF, mB = NEGINF;
            const u32* rw = (const u32*)(relL + (i + 1) * N_ + base);
            #pragma unroll
            for (int g = 0; g < NJ / 4; ++g) {
                u32 d = rw[g];
                #pragma unroll
                for (int bb = 0; bb < 4; ++bb) {
                    const int jj = 4 * g + bb;
                    u32 rr = (d >> (bb * 8)) & 255u;
                    u32 pr = relW32[(rr << 5) + p];
                    float rwbA = __uint_as_float(pr << 16);
                    float rwbB = __uint_as_float(pr & 0xffff0000u);
                    float dd = dreg[jj];
                    mA = fmaxf(mA, fmaxf(hA[jj] + rwbA, 0.f) * dd);
                    mB = fmaxf(mB, fmaxf(hB[jj] + rwbB, 0.f) * dd);
                }
            }
            combine_write(mA, mB, e, pmaxF + ((i & 1) ^ 1) * 192 + (w << 6));
        }
        BARRIER();                                        // step barrier
    }
}

// ---------------- precompute kernel v2 (unchanged) ----------------
__global__ __launch_bounds__(256, 2) void ggnn_pre(
    const int* __restrict__ node_slice, const int* __restrict__ type_slice,
    const float* __restrict__ emb_table, const float* __restrict__ type_table,
    const float* __restrict__ W_in,
    const float* __restrict__ Wr, const float* __restrict__ br,
    const float* __restrict__ Wz, const float* __restrict__ bz,
    const float* __restrict__ Wt, const float* __restrict__ bt,
    u16* __restrict__ NTbf, float* __restrict__ Hws)
{
    const int b  = blockIdx.x >> 4;
    const int i0 = (blockIdx.x & 15) * 8;
    const int t = threadIdx.x;
    const int w = t >> 6;
    const int e = t & 63;

    float wc[96];
    float bias = 0.f;
    if (w < 3) {
        const float* W  = (w == 0) ? Wr : (w == 1) ? Wz : Wt;
        const float* bb = (w == 0) ? br : (w == 1) ? bz : bt;
        bias = bb[e];
        #pragma unroll
        for (int k = 0; k < 96; ++k) wc[k] = W[k * 64 + e];
    } else {
        #pragma unroll
        for (int k = 0; k < 64; ++k) wc[k] = W_in[k * 64 + e];
        #pragma unroll
        for (int k = 64; k < 96; ++k) wc[k] = 0.f;
    }

    int nodes[8], typs[8];
    #pragma unroll
    for (int r = 0; r < 8; ++r) {
        nodes[r] = node_slice[b * N_ + i0 + r];
        typs[r]  = type_slice[b * N_ + i0 + r];
    }

    float xa[8], xb[8];
    #pragma unroll
    for (int r = 0; r < 8; ++r) {
        const float* pa = (e < 32)
            ? (type_table + (size_t)typs[r] * 32 + e)
            : (emb_table + (size_t)nodes[r] * 64 + (e - 32));
        xa[r] = *pa;
        xb[r] = emb_table[(size_t)nodes[r] * 64 + 32 + (e & 31)];
    }

    #pragma unroll
    for (int r = 0; r < 8; ++r) {
        if (w < 3) {
            float a0 = bias, a1 = 0.f, a2 = 0.f, a3 = 0.f;
            #pragma unroll
            for (int k = 0; k < 32; k += 4) {
                a0 += rlane(xa[r], k)     * wc[k];
                a1 += rlane(xa[r], k + 1) * wc[k + 1];
                a2 += rlane(xa[r], k + 2) * wc[k + 2];
                a3 += rlane(xa[r], k + 3) * wc[k + 3];
            }
            #pragma unroll
            for (int k = 0; k < 32; k += 4) {
                a0 += rlane(xa[r], 32 + k)     * wc[32 + k];
                a1 += rlane(xa[r], 32 + k + 1) * wc[32 + k + 1];
                a2 += rlane(xa[r], 32 + k + 2) * wc[32 + k + 2];
                a3 += rlane(xa[r], 32 + k + 3) * wc[32 + k + 3];
            }
            #pragma unroll
            for (int k = 32; k < 64; k += 4) {
                a0 += rlane(xb[r], k - 32) * wc[32 + k];
                a1 += rlane(xb[r], k - 31) * wc[32 + k + 1];
                a2 += rlane(xb[r], k - 30) * wc[32 + k + 2];
                a3 += rlane(xb[r], k - 29) * wc[32 + k + 3];
            }
            NTbf[(size_t)(b * N_ + i0 + r) * 192 + w * 64 + e] =
                f2b((a0 + a1) + (a2 + a3));
        } else {
            float a0 = 0.f, a1 = 0.f, a2 = 0.f, a3 = 0.f;
            #pragma unroll
            for (int k = 0; k < 32; k += 4) {
                a0 += rlane(xa[r], 32 + k)     * wc[k];
                a1 += rlane(xa[r], 32 + k + 1) * wc[k + 1];
                a2 += rlane(xa[r], 32 + k + 2) * wc[k + 2];
                a3 += rlane(xa[r], 32 + k + 3) * wc[k + 3];
            }
            #pragma unroll
            for (int k = 32; k < 64; k += 4) {
                a0 += rlane(xb[r], k - 32) * wc[k];
                a1 += rlane(xb[r], k - 31) * wc[k + 1];
                a2 += rlane(xb[r], k - 30) * wc[k + 2];
                a3 += rlane(xb[r], k - 29) * wc[k + 3];
            }
            Hws[(size_t)(b * N_ + i0 + r) * 64 + e] = (a0 + a1) + (a2 + a3);
        }
    }
}

// ---------------- main scan kernel v12 ----------------
__global__ __launch_bounds__(256, 1) void ggnn_main(
    const int* __restrict__ rel_matrix,
    const int* __restrict__ input_length, const float* __restrict__ distance,
    const float* __restrict__ rel_table,
    const float* __restrict__ W_in, const float* __restrict__ b_in,
    const float* __restrict__ Wr, const float* __restrict__ Wz, const float* __restrict__ Wt,
    const float* __restrict__ W_co, const float* __restrict__ b_co,
    const float* __restrict__ W1, const float* __restrict__ b1,
    const float* __restrict__ W2, const float* __restrict__ b2,
    const float* __restrict__ W3, const float* __restrict__ b3,
    const float* __restrict__ W4, const float* __restrict__ b4,
    const u16* __restrict__ NTbf, const float* __restrict__ Hws,
    float* __restrict__ out)
{
    __shared__ __align__(16) u32   relW32[51 * 32];       // 6.4 KB, [r][e-pair]
    __shared__ __align__(16) unsigned char relL[128 * 128]; // 16 KB, len-masked
    __shared__ __align__(16) float disc[N_];
    __shared__ __align__(16) u32   sub_l[128];            // saved subdiagonal
    __shared__ __align__(16) float pmaxF[2 * 192];        // parity x 3 slots
    __shared__ __align__(16) float updH[64];
    __shared__ __align__(16) float4 wTH[4 * 16 * 64];     // 64 KB: [tbl][kc][e]
    __shared__ __align__(16) float userrow[64], itemrow[64], submrow[64];
    __shared__ __align__(16) float temp[192];
    __shared__ float h1[128];
    __shared__ float h2v[64];
    __shared__ float h3v[32];

    const int b = blockIdx.x;
    const int t = threadIdx.x;
    const int w = t >> 6;          // 0..3
    const int e = t & 63;
    const int p = e & 31;
    const int half = e >> 5;
    const int len = input_length[b];
    const float NEGINF = -__builtin_inff();

    // ---- staging phase 1 ----
    if (t < N_) disc[t] = -0.1f * distance[b * N_ + t];

    {   // rel_matrix -> u8, len-masked
        const int4* src = (const int4*)(rel_matrix + b * N_ * N_);
        u32* dst = (u32*)relL;
        for (int c = t; c < 4096; c += 256) {
            int4 v = src[c];
            int j = (c * 4) & 127;
            u32 pk = (u32)((j + 0 < len && v.x) ? v.x : 0)
                   | ((u32)((j + 1 < len && v.y) ? v.y : 0) << 8)
                   | ((u32)((j + 2 < len && v.z) ? v.z : 0) << 16)
                   | ((u32)((j + 3 < len && v.w) ? v.w : 0) << 24);
            dst[c] = pk;
        }
    }
    for (int idx = t; idx < 51 * 32; idx += 256) {        // relW32 = b_in + rel@W_in_bot
        int r = idx >> 5, pp = idx & 31;
        float aA = b_in[2 * pp], aB = b_in[2 * pp + 1];
        #pragma unroll
        for (int k = 0; k < 32; ++k) {
            float rt = rel_table[r * 32 + k];
            aA += rt * W_in[(64 + k) * 64 + 2 * pp];
            aB += rt * W_in[(64 + k) * 64 + 2 * pp + 1];
        }
        relW32[idx] = (u32)f2b(aA) | ((u32)f2b(aB) << 16);
    }
    {   // wTH: [tbl][kc][e] float4; 0=Wr_bot 1=Wz_bot 2=Wt_bot 3=W_in_top
        float* wf = (float*)wTH;
        for (int idx = t; idx < 16384; idx += 256) {
            int tbl = idx >> 12;
            int rem = idx & 4095;
            int kc  = rem >> 8;
            int ee  = (rem >> 2) & 63;
            int d   = idx & 3;
            int k   = kc * 4 + d;
            float v;
            if      (tbl == 0) v = Wr[(96 + k) * 64 + ee];
            else if (tbl == 1) v = Wz[(96 + k) * 64 + ee];
            else if (tbl == 2) v = Wt[(96 + k) * 64 + ee];
            else               v = W_in[k * 64 + ee];
            wf[idx] = v;
        }
    }
    __syncthreads();                                      // staging visible

    // ---- staging phase 2: subdiag save+zero, +INF sentinel ----
    if (t < 127) {
        u32 v = relL[(t + 1) * N_ + t];
        sub_l[t] = v;
        relL[(t + 1) * N_ + t] = 0;
    }
    if (t == 127) sub_l[127] = 0;
    if (t < 32) relW32[t] = 0x7f807f80u;                  // r=0 -> +inf pair
    __syncthreads();

    if (w < 3) {
        // ---- B-waves: H owners + pmax producer ----
        if (w == 2) bloop<16>(b, w, e, p, half, len, Hws, relL, relW32,
                              disc, pmaxF, updH);
        else        bloop<24>(b, w, e, p, half, len, Hws, relL, relW32,
                              disc, pmaxF, updH);
    } else {
        // ---- GRU wave: full chain; ALL weight columns via LDS b128 ----
        const float4* wrL = wTH + e;            // tbl 0
        const float4* wzL = wTH + 1024 + e;     // tbl 1
        const float4* wtL = wTH + 2048 + e;     // tbl 2
        const float4* whL = wTH + 3072 + e;     // tbl 3

        const u16* NTb = NTbf + (size_t)b * N_ * 192;
        u16 ncr = NTb[e], ncz = NTb[64 + e], nct = NTb[128 + e];
        float uH = 0.f;
        float user_r = 0.f, item_r = 0.f, subm_r = NEGINF;
        u32 prn = 0x7f807f80u;                  // step-0 patch = no-op
        float ddn = -1.0f;
        BARRIER();                                        // prologue barrier

        for (int i = 0; i < len; ++i) {
            const float* pm = pmaxF + (i & 1) * 192;
            float mm = fmaxf(fmaxf(pm[e], pm[64 + e]), pm[128 + e]);
            {   // fresh-col patch, branch-free (prn=+inf pair -> no-op)
                float rwb = __uint_as_float((e & 1) ? (prn & 0xffff0000u)
                                                    : (prn << 16));
                mm = fmaxf(mm, fmaxf(uH + rwb, 0.f) * ddn);
            }
            float dis0 = (mm == NEGINF) ? 0.f : mm;

            // prefetch patch inputs for step i+1 (static LDS data)
            u32 rb2 = sub_l[i];
            u32 pr2 = relW32[(rb2 << 5) + (e >> 1)];
            float dd2 = disc[i];

            // NT prefetch for step i+1 (global, stays in flight)
            const int nrow = ((i + 1) & 127) * 192;
            u16 npr = NTb[nrow + e], npz = NTb[nrow + 64 + e],
                npt = NTb[nrow + 128 + e];

            // combined r,z matvec (LDS b128 columns)
            float ra0 = b2f(ncr), ra1 = 0.f, ra2 = 0.f, ra3 = 0.f;
            float za0 = b2f(ncz), za1 = 0.f, za2 = 0.f, za3 = 0.f;
            #pragma unroll
            for (int kc = 0; kc < 16; ++kc) {
                float4 wr = wrL[kc * 64];
                float4 wz = wzL[kc * 64];
                float s0 = rlane(dis0, 4 * kc),     s1 = rlane(dis0, 4 * kc + 1);
                float s2 = rlane(dis0, 4 * kc + 2), s3 = rlane(dis0, 4 * kc + 3);
                ra0 += s0 * wr.x; za0 += s0 * wz.x;
                ra1 += s1 * wr.y; za1 += s1 * wz.y;
                ra2 += s2 * wr.z; za2 += s2 * wz.z;
                ra3 += s3 * wr.w; za3 += s3 * wz.w;
            }
            float r = sigmoidf_((ra0 + ra1) + (ra2 + ra3));
            float z = sigmoidf_((za0 + za1) + (za2 + za3));
            float rdp = r * dis0;

            // t matvec (LDS b128 columns)
            float ta0 = b2f(nct), ta1 = 0.f, ta2 = 0.f, ta3 = 0.f;
            #pragma unroll
            for (int kc = 0; kc < 16; ++kc) {
                float4 wv = wtL[kc * 64];
                float s0 = rlane(rdp, 4 * kc),     s1 = rlane(rdp, 4 * kc + 1);
                float s2 = rlane(rdp, 4 * kc + 2), s3 = rlane(rdp, 4 * kc + 3);
                ta0 += s0 * wv.x; ta1 += s1 * wv.y;
                ta2 += s2 * wv.z; ta3 += s3 * wv.w;
            }
            float hh = tanhf_((ta0 + ta1) + (ta2 + ta3));
            float upd = (1.f - z) * dis0 + z * hh;
            if (i == 0) user_r = upd;
            subm_r = fmaxf(subm_r, upd);
            item_r = upd;

            // H matvec (LDS b128 columns)
            float ha0 = 0.f, ha1 = 0.f, ha2 = 0.f, ha3 = 0.f;
            #pragma unroll
            for (int kc = 0; kc < 16; ++kc) {
                float4 wv = whL[kc * 64];
                float s0 = rlane(upd, 4 * kc),     s1 = rlane(upd, 4 * kc + 1);
                float s2 = rlane(upd, 4 * kc + 2), s3 = rlane(upd, 4 * kc + 3);
                ha0 += s0 * wv.x; ha1 += s1 * wv.y;
                ha2 += s2 * wv.z; ha3 += s3 * wv.w;
            }
            uH = (ha0 + ha1) + (ha2 + ha3);
            updH[e] = uH;

            ncr = npr; ncz = npz; nct = npt;
            prn = pr2; ddn = dd2;
            BARRIER();                                    // step barrier
        }
        userrow[e] = user_r; itemrow[e] = item_r; submrow[e] = subm_r;
    }
    __syncthreads();

    // ---- epilogue ----
    if (t < 128) {
        const int half2 = t >> 6;               // 0: ua*user, 1: ia*item
        const float* row = (half2 == 0) ? userrow : itemrow;
        float acc = b_co[e];
        #pragma unroll
        for (int k = 0; k < 64; ++k) acc += row[k] * W_co[k * 64 + e];
        #pragma unroll
        for (int k = 0; k < 64; ++k) acc += submrow[k] * W_co[(64 + k) * 64 + e];
        float act = fmaxf(acc, 0.f);
        temp[half2 * 128 + e] = act * row[e];
    } else if (t < 192) {
        temp[64 + (t - 128)] = submrow[t - 128];
    }
    __syncthreads();

    if (t < 128) {
        float acc = b1[t];
        for (int k = 0; k < 192; ++k) acc += temp[k] * W1[k * 128 + t];
        h1[t] = fmaxf(acc, 0.f);
    }
    __syncthreads();
    if (t < 64) {
        float acc = b2[t];
        for (int k = 0; k < 128; ++k) acc += h1[k] * W2[k * 64 + t];
        h2v[t] = fmaxf(acc, 0.f);
    }
    __syncthreads();
    if (t < 32) {
        float acc = b3[t];
        for (int k = 0; k < 64; ++k) acc += h2v[k] * W3[k * 32 + t];
        h3v[t] = fmaxf(acc, 0.f);
    }
    __syncthreads();
    if (t == 0) {
        float acc = b4[0];
        for (int k = 0; k < 32; ++k) acc += h3v[k] * W4[k];
        out[b] = sigmoidf_(acc);
    }
}

extern "C" void kernel_launch(void* const* d_in, const int* in_sizes, int n_in,
                              void* d_out, int out_size, void* d_ws, size_t ws_size,
                              hipStream_t stream)
{
    const int*   node_slice = (const int*)d_in[0];
    const int*   type_slice = (const int*)d_in[1];
    const float* distance   = (const float*)d_in[2];
    const int*   rel_matrix = (const int*)d_in[3];
    const int*   input_len  = (const int*)d_in[4];
    // d_in[5] = isBatch (ignored)
    const float* emb_table  = (const float*)d_in[6];
    const float* type_table = (const float*)d_in[7];
    const float* rel_table  = (const float*)d_in[8];
    const float* W_in = (const float*)d_in[9];  const float* b_in = (const float*)d_in[10];
    const float* Wr   = (const float*)d_in[11]; const float* br   = (const float*)d_in[12];
    const float* Wz   = (const float*)d_in[13]; const float* bz   = (const float*)d_in[14];
    const float* Wt   = (const float*)d_in[15]; const float* bt   = (const float*)d_in[16];
    const float* W_co = (const float*)d_in[17]; const float* b_co = (const float*)d_in[18];
    const float* W1   = (const float*)d_in[19]; const float* b1   = (const float*)d_in[20];
    const float* W2   = (const float*)d_in[21]; const float* b2   = (const float*)d_in[22];
    const float* W3   = (const float*)d_in[23]; const float* b3   = (const float*)d_in[24];
    const float* W4   = (const float*)d_in[25]; const float* b4   = (const float*)d_in[26];

    u16*   NTbf = (u16*)d_ws;                            // 128*128*192 bf16 = 6.29 MB
    float* Hws  = (float*)((char*)d_ws + (size_t)B_ * N_ * 192 * 2); // 4.19 MB

    ggnn_pre<<<dim3(2048), dim3(256), 0, stream>>>(
        node_slice, type_slice, emb_table, type_table,
        W_in, Wr, br, Wz, bz, Wt, bt, NTbf, Hws);

    ggnn_main<<<dim3(B_), dim3(256), 0, stream>>>(
        rel_matrix, input_len, distance, rel_table,
        W_in, b_in, Wr, Wz, Wt, W_co, b_co,
        W1, b1, W2, b2, W3, b3, W4, b4,
        NTbf, Hws, (float*)d_out);
}